// Round 9
// baseline (22.285 us; speedup 1.0000x reference)
//
#include <hip/hip_runtime.h>

#define HH 512
#define WW 512
#define NP 48    // B*C

typedef float f32x4 __attribute__((ext_vector_type(4)));

__device__ __forceinline__ float min3f(float a, float b, float c) {
    return fminf(fminf(a, b), c);
}
__device__ __forceinline__ float max3f(float a, float b, float c) {
    return fmaxf(fmaxf(a, b), c);
}
__device__ __forceinline__ float med3f(float a, float b, float c) {
    return __builtin_amdgcn_fmed3f(a, b, c);  // exact median, finite inputs
}

// Dense-layout row load. Lane L owns cols [4L,4L+3] (group A) and
// [256+4L,256+4L+3] (group B): each dwordx4 is 64 lanes x 16B contiguous.
// Halos via lane shuffles; group boundary (cols 255/256) via broadcasts.
// w[0..5] = group A window, w[6..11] = group B window.
__device__ __forceinline__ void load_row12(float w[12], const float* __restrict__ base,
                                           int rr, int lane) {
    if (rr >= 0 && rr < HH) {
        const float* rp = base + rr * WW;
        f32x4 a = *reinterpret_cast<const f32x4*>(rp + lane * 4);
        f32x4 b = *reinterpret_cast<const f32x4*>(rp + 256 + lane * 4);
        w[1] = a.x; w[2] = a.y; w[3] = a.z; w[4] = a.w;
        w[7] = b.x; w[8] = b.y; w[9] = b.z; w[10] = b.w;
        float lA = __shfl_up(a.w, 1, 64);
        float rA = __shfl_down(a.x, 1, 64);
        float lB = __shfl_up(b.w, 1, 64);
        float rB = __shfl_down(b.x, 1, 64);
        float aw63 = __shfl(a.w, 63, 64);   // col 255
        float bx0  = __shfl(b.x, 0, 64);    // col 256
        w[0]  = (lane == 0)  ? 0.f  : lA;   // image left edge
        w[5]  = (lane == 63) ? bx0  : rA;
        w[6]  = (lane == 0)  ? aw63 : lB;
        w[11] = (lane == 63) ? 0.f  : rB;   // image right edge
    } else {
#pragma unroll
        for (int j = 0; j < 12; ++j) w[j] = 0.f;
    }
}

// 6-col window of 3 rows -> 4 output px (Smith column-sort + fmed3 combine).
__device__ __forceinline__ void step6(const float* A, const float* B,
                                      const float* C, float o[4]) {
    float lo[6], mi[6], hi[6];
#pragma unroll
    for (int j = 0; j < 6; ++j) {
        lo[j] = min3f(A[j], B[j], C[j]);
        mi[j] = med3f(A[j], B[j], C[j]);
        hi[j] = max3f(A[j], B[j], C[j]);
    }
#pragma unroll
    for (int j = 0; j < 4; ++j) {
        o[j] = med3f(max3f(lo[j], lo[j + 1], lo[j + 2]),
                     med3f(mi[j], mi[j + 1], mi[j + 2]),
                     min3f(hi[j], hi[j + 1], hi[j + 2]));
    }
}

// TR=1, copy-like: one wave per output row. Minimal register state
// (3 rows x 12 = 36 + temps) -> high occupancy; every SIMD keeps
// independent waves' load bursts in flight continuously.
__global__ __launch_bounds__(256) void MF_10943576670363_kernel(
    const float* __restrict__ in, float* __restrict__ out) {
    // XCD-chunked bijective swizzle: 6144 blocks, 8 XCDs, 768 blocks/XCD;
    // adjacent row-waves (sharing 2 of 3 input rows) stay on one XCD's L2.
    int bid = blockIdx.x;
    int cpx = gridDim.x >> 3;
    int swz = (bid & 7) * cpx + (bid >> 3);

    int lane = threadIdx.x & 63;
    int g = swz * 4 + (threadIdx.x >> 6);  // global wave id
    int ty = g & 511;                       // output row
    int p  = g >> 9;                        // plane

    const float* base = in + (size_t)p * (HH * WW);
    float* obase = out + (size_t)p * (HH * WW);

    float w0[12], w1[12], w2[12];
    load_row12(w0, base, ty - 1, lane);
    load_row12(w1, base, ty,     lane);
    load_row12(w2, base, ty + 1, lane);

    float oA[4], oB[4];
    step6(&w0[0], &w1[0], &w2[0], oA);
    step6(&w0[6], &w1[6], &w2[6], oB);

    float* op = obase + ty * WW;
    f32x4 vA = {oA[0], oA[1], oA[2], oA[3]};
    f32x4 vB = {oB[0], oB[1], oB[2], oB[3]};
    *reinterpret_cast<f32x4*>(op + lane * 4) = vA;
    *reinterpret_cast<f32x4*>(op + 256 + lane * 4) = vB;
}

extern "C" void kernel_launch(void* const* d_in, const int* in_sizes, int n_in,
                              void* d_out, int out_size, void* d_ws, size_t ws_size,
                              hipStream_t stream) {
    const float* image = (const float*)d_in[0];
    float* out = (float*)d_out;
    // waves = NP * HH = 48*512 = 24576 -> 6144 blocks (4 waves each).
    int blocks = NP * HH / 4;
    MF_10943576670363_kernel<<<blocks, 256, 0, stream>>>(image, out);
}

// Round 10
// 20.421 us; speedup vs baseline: 1.0912x; 1.0912x over previous
//
#include <hip/hip_runtime.h>

#define HH 512
#define WW 512
#define NP 48    // B*C
#define TR 8     // output rows per thread; 10 input rows, 6-deep register ring

typedef float f32x4 __attribute__((ext_vector_type(4)));

__device__ __forceinline__ float min3f(float a, float b, float c) {
    return fminf(fminf(a, b), c);
}
__device__ __forceinline__ float max3f(float a, float b, float c) {
    return fmaxf(fmaxf(a, b), c);
}
__device__ __forceinline__ float med3f(float a, float b, float c) {
    return __builtin_amdgcn_fmed3f(a, b, c);  // exact median, finite inputs
}

// Dense-layout row load. Lane L owns cols [4L,4L+3] (group A) and
// [256+4L,256+4L+3] (group B): each dwordx4 is 64 lanes x 16B contiguous.
// Halos via lane shuffles; group boundary (cols 255/256) via broadcasts.
// w[0..5] = group A window, w[6..11] = group B window.
__device__ __forceinline__ void load_row12(float w[12], const float* __restrict__ base,
                                           int rr, int lane) {
    if (rr >= 0 && rr < HH) {
        const float* rp = base + rr * WW;
        f32x4 a = *reinterpret_cast<const f32x4*>(rp + lane * 4);
        f32x4 b = *reinterpret_cast<const f32x4*>(rp + 256 + lane * 4);
        w[1] = a.x; w[2] = a.y; w[3] = a.z; w[4] = a.w;
        w[7] = b.x; w[8] = b.y; w[9] = b.z; w[10] = b.w;
        float lA = __shfl_up(a.w, 1, 64);
        float rA = __shfl_down(a.x, 1, 64);
        float lB = __shfl_up(b.w, 1, 64);
        float rB = __shfl_down(b.x, 1, 64);
        float aw63 = __shfl(a.w, 63, 64);   // col 255
        float bx0  = __shfl(b.x, 0, 64);    // col 256
        w[0]  = (lane == 0)  ? 0.f  : lA;   // image left edge
        w[5]  = (lane == 63) ? bx0  : rA;
        w[6]  = (lane == 0)  ? aw63 : lB;
        w[11] = (lane == 63) ? 0.f  : rB;   // image right edge
    } else {
#pragma unroll
        for (int j = 0; j < 12; ++j) w[j] = 0.f;
    }
}

// 6-col window of 3 rows -> 4 output px (Smith column-sort + fmed3 combine).
__device__ __forceinline__ void step6(const float* A, const float* B,
                                      const float* C, float o[4]) {
    float lo[6], mi[6], hi[6];
#pragma unroll
    for (int j = 0; j < 6; ++j) {
        lo[j] = min3f(A[j], B[j], C[j]);
        mi[j] = med3f(A[j], B[j], C[j]);
        hi[j] = max3f(A[j], B[j], C[j]);
    }
#pragma unroll
    for (int j = 0; j < 4; ++j) {
        o[j] = med3f(max3f(lo[j], lo[j + 1], lo[j + 2]),
                     med3f(mi[j], mi[j + 1], mi[j + 2]),
                     min3f(hi[j], hi[j + 1], hi[j + 2]));
    }
}

__global__ __launch_bounds__(256) void MF_10943576670363_kernel(
    const float* __restrict__ in, float* __restrict__ out) {
    // XCD-chunked bijective swizzle: 768 blocks, 8 XCDs, 96 blocks/XCD.
    int bid = blockIdx.x;
    int cpx = gridDim.x >> 3;
    int swz = (bid & 7) * cpx + (bid >> 3);

    int lane = threadIdx.x & 63;
    int g = swz * 4 + (threadIdx.x >> 6);  // global wave id
    int ty = g & 63;                        // H/TR = 64 row strips
    int p  = g >> 6;                        // plane

    int r0 = ty * TR;
    const float* base = in + (size_t)p * (HH * WW);
    float* obase = out + (size_t)p * (HH * WW);

    // 6-deep register ring, statically indexed (fully unrolled loop).
    float rb[6][12];
#pragma unroll
    for (int k = 0; k < 5; ++k) load_row12(rb[k], base, r0 + k - 1, lane);

#pragma unroll
    for (int i = 0; i < TR; ++i) {
        if (i < 5) load_row12(rb[(i + 5) % 6], base, r0 + i + 4, lane);
        float oA[4], oB[4];
        step6(&rb[i % 6][0], &rb[(i + 1) % 6][0], &rb[(i + 2) % 6][0], oA);
        step6(&rb[i % 6][6], &rb[(i + 1) % 6][6], &rb[(i + 2) % 6][6], oB);
        float* op = obase + (r0 + i) * WW;
        f32x4 vA = {oA[0], oA[1], oA[2], oA[3]};
        f32x4 vB = {oB[0], oB[1], oB[2], oB[3]};
        // Output is never re-read: nontemporal stores bypass L2, leaving
        // L2 capacity for the halo-row re-reads (the only remaining slack).
        __builtin_nontemporal_store(vA, reinterpret_cast<f32x4*>(op + lane * 4));
        __builtin_nontemporal_store(vB, reinterpret_cast<f32x4*>(op + 256 + lane * 4));
    }
}

extern "C" void kernel_launch(void* const* d_in, const int* in_sizes, int n_in,
                              void* d_out, int out_size, void* d_ws, size_t ws_size,
                              hipStream_t stream) {
    const float* image = (const float*)d_in[0];
    float* out = (float*)d_out;
    // waves = NP * (HH/TR) = 48*64 = 3072 -> 768 blocks = 12 waves/CU.
    int blocks = NP * (HH / TR) / 4;
    MF_10943576670363_kernel<<<blocks, 256, 0, stream>>>(image, out);
}